// Round 14
// baseline (59.462 us; speedup 1.0000x reference)
//
#include <hip/hip_runtime.h>
#include <math.h>

#define NSAMP 16384
#define ND    512

typedef float f2 __attribute__((ext_vector_type(2)));
__device__ __forceinline__ f2 spl(float x) { return (f2){x, x}; }

// ---------------- cross-lane primitives ----------------
template<int CTRL>
__device__ __forceinline__ float dppf(float x) {
  return __int_as_float(__builtin_amdgcn_update_dpp(
      __float_as_int(x), __float_as_int(x), CTRL, 0xF, 0xF, true));
}
template<int CTRL, int RM, int BM>
__device__ __forceinline__ float dppf_keep(float x) {
  return __int_as_float(__builtin_amdgcn_update_dpp(
      __float_as_int(x), __float_as_int(x), CTRL, RM, BM, false));
}
template<int P>
__device__ __forceinline__ float swzf(float x) {
  return __int_as_float(__builtin_amdgcn_ds_swizzle(__float_as_int(x), P));
}
__device__ __forceinline__ float bpermf(int addrB, float x) {
  return __int_as_float(__builtin_amdgcn_ds_bpermute(addrB, __float_as_int(x)));
}

#if __has_builtin(__builtin_amdgcn_permlane16_swap)
#define HAVE_PLSWAP 1
#endif
__device__ __forceinline__ void plswap16(float x, float& a, float& b) {
#ifdef HAVE_PLSWAP
  auto r = __builtin_amdgcn_permlane16_swap(__float_as_uint(x), __float_as_uint(x), false, false);
  a = __uint_as_float(r[0]); b = __uint_as_float(r[1]);
#else
  a = x; b = swzf<0x401F>(x);
#endif
}
__device__ __forceinline__ void plswap32(float x, float& a, float& b) {
#ifdef HAVE_PLSWAP
  auto r = __builtin_amdgcn_permlane32_swap(__float_as_uint(x), __float_as_uint(x), false, false);
  a = __uint_as_float(r[0]); b = __uint_as_float(r[1]);
#else
  a = x; b = __shfl_xor(x, 32, 64);
#endif
}

// butterfly exchange of an (re,im) pair: value of lane (lane ^ M)
template<int M>
__device__ __forceinline__ f2 bfly2(f2 x) {
  f2 r;
  if constexpr (M == 1)       { r.x = dppf<0xB1>(x.x);    r.y = dppf<0xB1>(x.y); }
  else if constexpr (M == 2)  { r.x = dppf<0x4E>(x.x);    r.y = dppf<0x4E>(x.y); }
  else if constexpr (M == 8)  { r.x = dppf<0x128>(x.x);   r.y = dppf<0x128>(x.y); }
  else if constexpr (M == 4)  { r.x = swzf<0x101F>(x.x);  r.y = swzf<0x101F>(x.y); }
  else if constexpr (M == 16) { r.x = swzf<0x401F>(x.x);  r.y = swzf<0x401F>(x.y); }
  else                        { r.x = __shfl_xor(x.x, 32, 64); r.y = __shfl_xor(x.y, 32, 64); }
  return r;
}

// dual-sample interleaved: sum over all 64 lanes of y[lane&7]
__device__ __forceinline__ void fold8_allsum2(const float* yA, const float* yB,
                                              int lane, float& rA, float& rB) {
  float a4[4], b4[4];
#pragma unroll
  for (int i = 0; i < 4; ++i) {
    float kA = (lane & 1) ? yA[2 * i + 1] : yA[2 * i];
    float sA = (lane & 1) ? yA[2 * i]     : yA[2 * i + 1];
    float kB = (lane & 1) ? yB[2 * i + 1] : yB[2 * i];
    float sB = (lane & 1) ? yB[2 * i]     : yB[2 * i + 1];
    a4[i] = kA + dppf<0xB1>(sA);
    b4[i] = kB + dppf<0xB1>(sB);
  }
  float a2[2], b2[2];
#pragma unroll
  for (int i = 0; i < 2; ++i) {
    float kA = (lane & 2) ? a4[2 * i + 1] : a4[2 * i];
    float sA = (lane & 2) ? a4[2 * i]     : a4[2 * i + 1];
    float kB = (lane & 2) ? b4[2 * i + 1] : b4[2 * i];
    float sB = (lane & 2) ? b4[2 * i]     : b4[2 * i + 1];
    a2[i] = kA + dppf<0x4E>(sA);
    b2[i] = kB + dppf<0x4E>(sB);
  }
  float kA = (lane & 4) ? a2[1] : a2[0];
  float sA = (lane & 4) ? a2[0] : a2[1];
  float kB = (lane & 4) ? b2[1] : b2[0];
  float sB = (lane & 4) ? b2[0] : b2[1];
  rA = kA + swzf<0x101F>(sA);
  rB = kB + swzf<0x101F>(sB);
  rA += dppf<0x128>(rA);
  rB += dppf<0x128>(rB);
  { float a, b; plswap16(rA, a, b); rA = a + b; }
  { float a, b; plswap16(rB, a, b); rB = a + b; }
  { float a, b; plswap32(rA, a, b); rA = a + b; }
  { float a, b; plswap32(rB, a, b); rB = a + b; }
}

// all-reduce sum within each 8-lane group
__device__ __forceinline__ float grp8_sum(float x) {
  x += dppf<0xB1>(x);
  x += dppf<0x4E>(x);
  x += swzf<0x101F>(x);
  return x;
}

// complex multiply
__device__ __forceinline__ f2 cmul(f2 a, f2 b) {
  f2 bs = __builtin_shufflevector(b, b, 1, 0);
  f2 t  = (f2){-a.y, a.y} * bs;
  return spl(a.x) * b + t;
}

// ---------------- gates on dual state: s[16], sample = r>>3, wire bits = r&7 ----------------
template<int LB>
__device__ __forceinline__ void ry_local(f2* s, float c, float sv) {
#pragma unroll
  for (int r0 = 0; r0 < 16; ++r0) {
    if ((r0 & 7) & (1 << LB)) continue;
    const int r1 = r0 | (1 << LB);
    f2 a0 = s[r0], a1 = s[r1];
    s[r0] = spl(c) * a0 - spl(sv) * a1;
    s[r1] = spl(sv) * a0 + spl(c) * a1;
  }
}
template<int LB>
__device__ __forceinline__ void rz_local(f2* s, f2 phm, f2 php) {
#pragma unroll
  for (int r = 0; r < 16; ++r) s[r] = cmul(s[r], ((r & 7) & (1 << LB)) ? php : phm);
}
template<int M>
__device__ __forceinline__ void ry_lane(f2* s, float c, float se) {
#pragma unroll
  for (int r = 0; r < 16; ++r) {
    f2 p = bfly2<M>(s[r]);
    s[r] = spl(c) * s[r] + spl(se) * p;
  }
}
template<int CB, int TB>
__device__ __forceinline__ void cnot_ll(f2* s) {
#pragma unroll
  for (int r0 = 0; r0 < 16; ++r0) {
    if (!((r0 & 7) & (1 << CB)) || ((r0 & 7) & (1 << TB))) continue;
    const int r1 = r0 | (1 << TB);
    f2 t = s[r0]; s[r0] = s[r1]; s[r1] = t;
  }
}
template<int CB, int TM>
__device__ __forceinline__ void cnot_lt(f2* s) {
#pragma unroll
  for (int r = 0; r < 16; ++r) {
    if (!((r & 7) & (1 << CB))) continue;
    s[r] = bfly2<TM>(s[r]);
  }
}
__device__ __forceinline__ void cnot_bperm(f2* s, int addrB) {
#pragma unroll
  for (int r = 0; r < 16; ++r) {
    s[r].x = bpermf(addrB, s[r].x);
    s[r].y = bpermf(addrB, s[r].y);
  }
}
// CNOT ctrl=m4 (banks 1,3), tgt=m1: masked quad_perm, others keep old
__device__ __forceinline__ void cnot_m4_t1(f2* s) {
#pragma unroll
  for (int r = 0; r < 16; ++r) {
    s[r].x = dppf_keep<0xB1, 0xF, 0xA>(s[r].x);
    s[r].y = dppf_keep<0xB1, 0xF, 0xA>(s[r].y);
  }
}
// CNOT ctrl=m1, tgt=m2: full quad_perm [0,3,2,1]
__device__ __forceinline__ void cnot_m1_t2(f2* s) {
#pragma unroll
  for (int r = 0; r < 16; ++r) {
    s[r].x = dppf<0x6C>(s[r].x);
    s[r].y = dppf<0x6C>(s[r].y);
  }
}
template<int TB>
__device__ __forceinline__ void cnot_tl(f2* s, bool cc) {
#pragma unroll
  for (int r0 = 0; r0 < 16; ++r0) {
    if ((r0 & 7) & (1 << TB)) continue;
    const int r1 = r0 | (1 << TB);
    f2 n0, n1;
    n0.x = cc ? s[r1].x : s[r0].x;  n0.y = cc ? s[r1].y : s[r0].y;
    n1.x = cc ? s[r0].x : s[r1].x;  n1.y = cc ? s[r0].y : s[r1].y;
    s[r0] = n0; s[r1] = n1;
  }
}

// ---------------- prekernel: layer trig table ----------------
__global__ void qpre_kernel(const float* __restrict__ qw, float* __restrict__ ws) {
  int t = threadIdx.x;
  if (t < 27) {
    float s, c; __sincosf(qw[9 + t] * 0.5f, &s, &c);
    ws[2 * t] = c; ws[2 * t + 1] = s;
  }
}

template<bool PRE>
struct Consts {
  const float* qw; const float* ws;
  __device__ __forceinline__ f2 ltrig(int l, int i) const {
    if constexpr (PRE) {
      return ((const f2*)ws)[(l - 1) * 9 + i];
    } else {
      float s, c; __sincosf(qw[l * 9 + i] * 0.5f, &s, &c);
      return (f2){c, s};
    }
  }
};

// One entangling layer (dual-sample). MODE semantics (all exact):
// 1: ancilla birth scalar; 2: CNOT(7,8) bperm, RY(8) dropped; 3: truncated tail.
template<bool PRE, int MODE>
__device__ __forceinline__ void do_layer(f2* st, int lane, const Consts<PRE>& cst, int l,
                                         int addr56, int addr67, int addr78) {
  f2 t[9];
#pragma unroll
  for (int i = 0; i < 9; ++i) t[i] = cst.ltrig(l, i);

  cnot_ll<0, 1>(st);                                       // CNOT(0,1)
  ry_local<0>(st, t[0].x, t[0].y);
  rz_local<0>(st, (f2){t[0].x, -t[0].y}, (f2){t[0].x, t[0].y});  // Z0 inline
  cnot_ll<1, 2>(st);                                       // CNOT(1,2)
  ry_local<1>(st, t[1].x, t[1].y);                         // Z1 deferred
  cnot_lt<2, 4>(st);                                       // CNOT(2,3)
  ry_local<2>(st, t[2].x, t[2].y);                         // Z2 deferred
  cnot_m4_t1(st);                                          // CNOT(3,4)
  { float se = (lane & 4) ? t[3].y : -t[3].y;
    ry_lane<4>(st, t[3].x, se); }                          // Z3 deferred
  cnot_m1_t2(st);                                          // CNOT(4,5)
  { float se = (lane & 1) ? t[4].y : -t[4].y;
    ry_lane<1>(st, t[4].x, se); }                          // Z4 deferred
  cnot_bperm(st, addr56);                                  // CNOT(5,6)
  { float se = (lane & 2) ? t[5].y : -t[5].y;
    ry_lane<2>(st, t[5].x, se); }                          // Z5 deferred
  cnot_bperm(st, addr67);                                  // CNOT(6,7)
  { float se = (lane & 8) ? t[6].y : -t[6].y;
    ry_lane<8>(st, t[6].x, se); }                          // Z6 deferred
  cnot_tl<0>(st, (lane & 16) != 0);                        // CNOT(7,0)
  { float se = (lane & 16) ? t[7].y : -t[7].y;
    ry_lane<16>(st, t[7].x, se); }                         // Z7 deferred

  if constexpr (MODE == 1) {
    const float wsel = (lane & 32) ? ((lane & 16) ? t[8].x : t[8].y)
                                   : ((lane & 16) ? -t[8].y : t[8].x);
#pragma unroll
    for (int r = 0; r < 16; ++r) st[r] = st[r] * spl(wsel);
  }
  if constexpr (MODE == 2) {
    cnot_bperm(st, addr78);                                // CNOT(7,8)
  }
  if constexpr (MODE != 3) {
    // merged deferred phase (shared across both samples)
    f2 L4[4];
#pragma unroll
    for (int k = 0; k < 4; ++k) {
      f2 p1 = (f2){t[1].x, (k & 1) ? t[1].y : -t[1].y};
      f2 p2 = (f2){t[2].x, (k & 2) ? t[2].y : -t[2].y};
      L4[k] = cmul(p1, p2);
    }
    f2 phW = (f2){t[3].x, (lane & 4)  ? t[3].y : -t[3].y};
    phW = cmul(phW, (f2){t[4].x, (lane & 1)  ? t[4].y : -t[4].y});
    phW = cmul(phW, (f2){t[5].x, (lane & 2)  ? t[5].y : -t[5].y});
    phW = cmul(phW, (f2){t[6].x, (lane & 8)  ? t[6].y : -t[6].y});
    phW = cmul(phW, (f2){t[7].x, (lane & 16) ? t[7].y : -t[7].y});
    f2 pr[4];
#pragma unroll
    for (int k = 0; k < 4; ++k) pr[k] = cmul(L4[k], phW);
#pragma unroll
    for (int r = 0; r < 16; ++r) st[r] = cmul(st[r], pr[((r & 7) >> 1) & 3]);
  }
}

// Wire->lane-bit map (wires 0,1,2 = register bits 0,1,2):
//   wire4->m1, wire5->m2, wire3->m4, wire6->m8, wire7->m16, wire8(anc)->m32
template<bool PRE>
__global__ __launch_bounds__(128, 8) void qlayer_kernel(
    const float* __restrict__ x, const float* __restrict__ tstep,
    const float* __restrict__ w_in, const float* __restrict__ b_in,
    const float* __restrict__ g, const float* __restrict__ be,
    const float* __restrict__ qw, const float* __restrict__ w_out,
    const float* __restrict__ b_out, float* __restrict__ out,
    const float* __restrict__ ws)
{
  __shared__ __align__(16) float s_u[2][2][8][4];  // per-wave, per-sample u table
  __shared__ __align__(16) float s_z[2][2][8];     // per-wave, per-sample z table

  const int tid    = threadIdx.x;
  const int lane   = tid & 63;
  const int wv     = tid >> 6;                  // 0..1 (128-thread block)
  const int smpA   = blockIdx.x * 4 + wv * 2;   // this wave's two samples
  const int smpB   = smpA + 1;
  const int jq     = lane & 7;
  const int dbase  = lane << 3;

  const int addr56 = (lane ^ ((lane & 2) << 2)) << 2;
  const int addr67 = (lane ^ ((lane & 8) << 1)) << 2;
  const int addr78 = (lane ^ ((lane & 16) << 1)) << 2;

  // ---------------- input GEMM (w_in loads shared by both samples) ----------------
  const float4* xrA = (const float4*)(x + (size_t)smpA * ND + dbase);
  const float4* xrB = (const float4*)(x + (size_t)smpB * ND + dbase);
  const float4 xaA = xrA[0], xbA = xrA[1];
  const float4 xaB = xrB[0], xbB = xrB[1];
  const f2 a0 = (f2){xaA.x, xaA.y}, a1 = (f2){xaA.z, xaA.w};
  const f2 a2 = (f2){xbA.x, xbA.y}, a3 = (f2){xbA.z, xbA.w};
  const f2 b0 = (f2){xaB.x, xaB.y}, b1 = (f2){xaB.z, xaB.w};
  const f2 b2 = (f2){xbB.x, xbB.y}, b3 = (f2){xbB.z, xbB.w};

  float hA[8], hB[8];
#pragma unroll
  for (int j = 0; j < 8; ++j) {
    const float4* wj = (const float4*)(w_in + j * ND + dbase);
    float4 wa = wj[0], wb = wj[1];
    f2 w0 = (f2){wa.x, wa.y}, w1 = (f2){wa.z, wa.w};
    f2 w2 = (f2){wb.x, wb.y}, w3 = (f2){wb.z, wb.w};
    f2 accA = a0 * w0 + a1 * w1 + a2 * w2 + a3 * w3;
    f2 accB = b0 * w0 + b1 * w1 + b2 * w2 + b3 * w3;
    hA[j] = accA.x + accA.y;
    hB[j] = accB.x + accB.y;
  }
  float HA, HB;
  fold8_allsum2(hA, hB, lane, HA, HB);

  // ---------------- per-qubit tanh+LN+angle (dual) ----------------
  const float t0  = tstep[0];
  const float bj  = b_in[jq];
  const float gj  = g[jq];
  const float bej = be[jq];
  float tjA, tjB;
  {
    float vA = fminf(15.f, fmaxf(-15.f, HA + bj));
    float vB = fminf(15.f, fmaxf(-15.f, HB + bj));
    float eA = __expf(2.f * vA), eB = __expf(2.f * vB);
    tjA = (eA - 1.f) * __builtin_amdgcn_rcpf(eA + 1.f);
    tjB = (eB - 1.f) * __builtin_amdgcn_rcpf(eB + 1.f);
  }
  const float muA = grp8_sum(tjA) * 0.125f;
  const float muB = grp8_sum(tjB) * 0.125f;
  const float dvA = tjA - muA, dvB = tjB - muB;
  const float varA = grp8_sum(dvA * dvA) * 0.125f;
  const float varB = grp8_sum(dvB * dvB) * 0.125f;
  const float angA = dvA * rsqrtf(varA + 1e-5f) * gj + bej + t0;
  const float angB = dvB * rsqrtf(varB + 1e-5f) * gj + bej + t0;

  // ---------------- u vectors (M shared across samples) ----------------
  {
    float s0, c0, s1, c1;
    __sincosf(qw[jq] * 0.5f, &s0, &c0);
    __sincosf(qw[9 + jq] * 0.5f, &s1, &c1);
    f2 M00 = (f2){ c1 * c0, -s1 * c0};
    f2 M01 = (f2){-s1 * s0, -c1 * s0};
    f2 M10 = (f2){ s1 * s0, -c1 * s0};
    f2 M11 = (f2){ c1 * c0,  s1 * c0};
    float saA, caA; __sincosf(angA * 0.5f, &saA, &caA);
    float saB, caB; __sincosf(angB * 0.5f, &saB, &caB);
    f2 v0A = spl(caA) * (f2){caA, -saA};
    f2 v1A = spl(saA) * (f2){saA, -caA};
    f2 v0B = spl(caB) * (f2){caB, -saB};
    f2 v1B = spl(saB) * (f2){saB, -caB};
    f2 u0A = cmul(M00, v0A) + cmul(M01, v1A);
    f2 u1A = cmul(M10, v0A) + cmul(M11, v1A);
    f2 u0B = cmul(M00, v0B) + cmul(M01, v1B);
    f2 u1B = cmul(M10, v0B) + cmul(M11, v1B);
    if (lane < 16) {
      const int sb = lane >> 3;
      f2 u0 = sb ? u0B : u0A;
      f2 u1 = sb ? u1B : u1A;
      *(float4*)&s_u[wv][sb][jq][0] = (float4){u0.x, u0.y, u1.x, u1.y};
    }
  }
  asm volatile("s_waitcnt lgkmcnt(0)" ::: "memory");
  __builtin_amdgcn_sched_barrier(0);

  // ---------------- build MIRRORED product states ----------------
  f2 st[16];
#pragma unroll
  for (int smp = 0; smp < 2; ++smp) {
    const f2* ub = (const f2*)&s_u[wv][smp][0][0];
    f2 r4 = ub[4 * 2 + ((lane >> 0) & 1)];
    f2 r5 = ub[5 * 2 + ((lane >> 1) & 1)];
    f2 r3 = ub[3 * 2 + ((lane >> 2) & 1)];
    f2 r6 = ub[6 * 2 + ((lane >> 3) & 1)];
    f2 r7 = ub[7 * 2 + ((lane >> 4) & 1)];
    f2 hl = cmul(cmul(cmul(cmul(r4, r5), r3), r6), r7);
    f2 u0q0 = ub[0], u1q0 = ub[1], u0q1 = ub[2], u1q1 = ub[3];
    f2 u0q2 = ub[4], u1q2 = ub[5];
    f2 t01[4];
#pragma unroll
    for (int q = 0; q < 4; ++q)
      t01[q] = cmul((q & 1) ? u1q0 : u0q0, (q & 2) ? u1q1 : u0q1);
#pragma unroll
    for (int r = 0; r < 8; ++r)
      st[smp * 8 + r] = cmul(cmul(t01[r & 3], (r & 4) ? u1q2 : u0q2), hl);
  }

  // ---------------- entangling layers ----------------
  Consts<PRE> cst{qw, ws};
  do_layer<PRE, 1>(st, lane, cst, 1, addr56, addr67, addr78);
  do_layer<PRE, 2>(st, lane, cst, 2, addr56, addr67, addr78);
  do_layer<PRE, 3>(st, lane, cst, 3, addr56, addr67, addr78);

  // ---------------- Z expectations (dual) ----------------
  float pA[8], pB[8];
#pragma unroll
  for (int r = 0; r < 8; ++r) {
    pA[r] = st[r].x * st[r].x + st[r].y * st[r].y;
    pB[r] = st[8 + r].x * st[8 + r].x + st[8 + r].y * st[8 + r].y;
  }
  float totA = 0.f, totB = 0.f;
#pragma unroll
  for (int r = 0; r < 8; ++r) { totA += pA[r]; totB += pB[r]; }

  float yA[8], yB[8];
  yA[0] = (pA[0] - pA[1]) + (pA[2] - pA[3]) + (pA[4] - pA[5]) + (pA[6] - pA[7]);
  yB[0] = (pB[0] - pB[1]) + (pB[2] - pB[3]) + (pB[4] - pB[5]) + (pB[6] - pB[7]);
  yA[1] = (pA[0] + pA[1]) - (pA[2] + pA[3]) + (pA[4] + pA[5]) - (pA[6] + pA[7]);
  yB[1] = (pB[0] + pB[1]) - (pB[2] + pB[3]) + (pB[4] + pB[5]) - (pB[6] + pB[7]);
  yA[2] = (pA[0] + pA[1] + pA[2] + pA[3]) - (pA[4] + pA[5] + pA[6] + pA[7]);
  yB[2] = (pB[0] + pB[1] + pB[2] + pB[3]) - (pB[4] + pB[5] + pB[6] + pB[7]);
  yA[3] = (lane & 4)  ? -totA : totA;  yB[3] = (lane & 4)  ? -totB : totB;
  yA[4] = (lane & 1)  ? -totA : totA;  yB[4] = (lane & 1)  ? -totB : totB;
  yA[5] = (lane & 2)  ? -totA : totA;  yB[5] = (lane & 2)  ? -totB : totB;
  yA[6] = (lane & 8)  ? -totA : totA;  yB[6] = (lane & 8)  ? -totB : totB;
  yA[7] = (lane & 16) ? -totA : totA;  yB[7] = (lane & 16) ? -totB : totB;
  float ZA, ZB;
  fold8_allsum2(yA, yB, lane, ZA, ZB);
  if (lane < 16) {
    const int sb = lane >> 3;
    s_z[wv][sb][jq] = sb ? ZB : ZA;
  }
  asm volatile("s_waitcnt lgkmcnt(0)" ::: "memory");
  __builtin_amdgcn_sched_barrier(0);

  const float4 zaA = *(const float4*)&s_z[wv][0][0];
  const float4 zbA = *(const float4*)&s_z[wv][0][4];
  const float4 zaB = *(const float4*)&s_z[wv][1][0];
  const float4 zbB = *(const float4*)&s_z[wv][1][4];

  // ---------------- epilogue (w_out/b_out loads shared) ----------------
  const f2 zA01 = (f2){zaA.x, zaA.y}, zA23 = (f2){zaA.z, zaA.w};
  const f2 zA45 = (f2){zbA.x, zbA.y}, zA67 = (f2){zbA.z, zbA.w};
  const f2 zB01 = (f2){zaB.x, zaB.y}, zB23 = (f2){zaB.z, zaB.w};
  const f2 zB45 = (f2){zbB.x, zbB.y}, zB67 = (f2){zbB.z, zbB.w};
  const float4* wo = (const float4*)(w_out + (size_t)dbase * 8);
  const float4* bo = (const float4*)(b_out + dbase);
  const float4 bo0 = bo[0], bo1 = bo[1];
  const float xkA[8] = {xaA.x, xaA.y, xaA.z, xaA.w, xbA.x, xbA.y, xbA.z, xbA.w};
  const float xkB[8] = {xaB.x, xaB.y, xaB.z, xaB.w, xbB.x, xbB.y, xbB.z, xbB.w};
  const float bk[8]  = {bo0.x, bo0.y, bo0.z, bo0.w, bo1.x, bo1.y, bo1.z, bo1.w};
  float oA[8], oB[8];
#pragma unroll
  for (int k = 0; k < 8; ++k) {
    float4 wa = wo[2 * k];
    float4 wb = wo[2 * k + 1];
    f2 w01 = (f2){wa.x, wa.y}, w23 = (f2){wa.z, wa.w};
    f2 w45 = (f2){wb.x, wb.y}, w67 = (f2){wb.z, wb.w};
    f2 accA = zA01 * w01 + zA23 * w23 + zA45 * w45 + zA67 * w67;
    f2 accB = zB01 * w01 + zB23 * w23 + zB45 * w45 + zB67 * w67;
    oA[k] = xkA[k] + bk[k] + accA.x + accA.y;
    oB[k] = xkB[k] + bk[k] + accB.x + accB.y;
  }
  float4* outA = (float4*)(out + (size_t)smpA * ND + dbase);
  float4* outB = (float4*)(out + (size_t)smpB * ND + dbase);
  outA[0] = (float4){oA[0], oA[1], oA[2], oA[3]};
  outA[1] = (float4){oA[4], oA[5], oA[6], oA[7]};
  outB[0] = (float4){oB[0], oB[1], oB[2], oB[3]};
  outB[1] = (float4){oB[4], oB[5], oB[6], oB[7]};
}

extern "C" void kernel_launch(void* const* d_in, const int* in_sizes, int n_in,
                              void* d_out, int out_size, void* d_ws, size_t ws_size,
                              hipStream_t stream) {
  const float* x     = (const float*)d_in[0];
  const float* ts    = (const float*)d_in[1];
  const float* w_in  = (const float*)d_in[2];
  const float* b_in  = (const float*)d_in[3];
  const float* g     = (const float*)d_in[4];
  const float* be    = (const float*)d_in[5];
  const float* qw    = (const float*)d_in[6];
  const float* w_out = (const float*)d_in[7];
  const float* b_out = (const float*)d_in[8];
  float* out = (float*)d_out;

  const bool pre = (d_ws != nullptr) && (ws_size >= 256);
  if (pre) {
    qpre_kernel<<<dim3(1), dim3(64), 0, stream>>>(qw, (float*)d_ws);
    qlayer_kernel<true><<<dim3(NSAMP / 4), dim3(128), 0, stream>>>(
        x, ts, w_in, b_in, g, be, qw, w_out, b_out, out, (const float*)d_ws);
  } else {
    qlayer_kernel<false><<<dim3(NSAMP / 4), dim3(128), 0, stream>>>(
        x, ts, w_in, b_in, g, be, qw, w_out, b_out, out, (const float*)d_ws);
  }
}

// Round 15
// 56.459 us; speedup vs baseline: 1.0532x; 1.0532x over previous
//
#include <hip/hip_runtime.h>
#include <math.h>

#define NSAMP 16384
#define ND    512

typedef float f2 __attribute__((ext_vector_type(2)));
__device__ __forceinline__ f2 spl(float x) { return (f2){x, x}; }

// ---------------- cross-lane primitives ----------------
template<int CTRL>
__device__ __forceinline__ float dppf(float x) {
  return __int_as_float(__builtin_amdgcn_update_dpp(
      __float_as_int(x), __float_as_int(x), CTRL, 0xF, 0xF, true));
}
template<int CTRL, int RM, int BM>
__device__ __forceinline__ float dppf_keep(float x) {
  return __int_as_float(__builtin_amdgcn_update_dpp(
      __float_as_int(x), __float_as_int(x), CTRL, RM, BM, false));
}
template<int P>
__device__ __forceinline__ float swzf(float x) {
  return __int_as_float(__builtin_amdgcn_ds_swizzle(__float_as_int(x), P));
}
__device__ __forceinline__ float bpermf(int addrB, float x) {
  return __int_as_float(__builtin_amdgcn_ds_bpermute(addrB, __float_as_int(x)));
}

#if __has_builtin(__builtin_amdgcn_permlane16_swap)
#define HAVE_PLSWAP 1
#endif
__device__ __forceinline__ void plswap16(float x, float& a, float& b) {
#ifdef HAVE_PLSWAP
  auto r = __builtin_amdgcn_permlane16_swap(__float_as_uint(x), __float_as_uint(x), false, false);
  a = __uint_as_float(r[0]); b = __uint_as_float(r[1]);
#else
  a = x; b = swzf<0x401F>(x);
#endif
}
__device__ __forceinline__ void plswap32(float x, float& a, float& b) {
#ifdef HAVE_PLSWAP
  auto r = __builtin_amdgcn_permlane32_swap(__float_as_uint(x), __float_as_uint(x), false, false);
  a = __uint_as_float(r[0]); b = __uint_as_float(r[1]);
#else
  a = x; b = __shfl_xor(x, 32, 64);
#endif
}

// butterfly exchange of an (re,im) pair: value of lane (lane ^ M)
template<int M>
__device__ __forceinline__ f2 bfly2(f2 x) {
  f2 r;
  if constexpr (M == 1)       { r.x = dppf<0xB1>(x.x);    r.y = dppf<0xB1>(x.y); }
  else if constexpr (M == 2)  { r.x = dppf<0x4E>(x.x);    r.y = dppf<0x4E>(x.y); }
  else if constexpr (M == 8)  { r.x = dppf<0x128>(x.x);   r.y = dppf<0x128>(x.y); }
  else if constexpr (M == 4)  { r.x = swzf<0x101F>(x.x);  r.y = swzf<0x101F>(x.y); }
  else if constexpr (M == 16) { r.x = swzf<0x401F>(x.x);  r.y = swzf<0x401F>(x.y); }
  else                        { r.x = __shfl_xor(x.x, 32, 64); r.y = __shfl_xor(x.y, 32, 64); }
  return r;
}

// dual-sample interleaved: sum over all 64 lanes of y[lane&7]
__device__ __forceinline__ void fold8_allsum2(const float* yA, const float* yB,
                                              int lane, float& rA, float& rB) {
  float a4[4], b4[4];
#pragma unroll
  for (int i = 0; i < 4; ++i) {
    float kA = (lane & 1) ? yA[2 * i + 1] : yA[2 * i];
    float sA = (lane & 1) ? yA[2 * i]     : yA[2 * i + 1];
    float kB = (lane & 1) ? yB[2 * i + 1] : yB[2 * i];
    float sB = (lane & 1) ? yB[2 * i]     : yB[2 * i + 1];
    a4[i] = kA + dppf<0xB1>(sA);
    b4[i] = kB + dppf<0xB1>(sB);
  }
  float a2[2], b2[2];
#pragma unroll
  for (int i = 0; i < 2; ++i) {
    float kA = (lane & 2) ? a4[2 * i + 1] : a4[2 * i];
    float sA = (lane & 2) ? a4[2 * i]     : a4[2 * i + 1];
    float kB = (lane & 2) ? b4[2 * i + 1] : b4[2 * i];
    float sB = (lane & 2) ? b4[2 * i]     : b4[2 * i + 1];
    a2[i] = kA + dppf<0x4E>(sA);
    b2[i] = kB + dppf<0x4E>(sB);
  }
  float kA = (lane & 4) ? a2[1] : a2[0];
  float sA = (lane & 4) ? a2[0] : a2[1];
  float kB = (lane & 4) ? b2[1] : b2[0];
  float sB = (lane & 4) ? b2[0] : b2[1];
  rA = kA + swzf<0x101F>(sA);
  rB = kB + swzf<0x101F>(sB);
  rA += dppf<0x128>(rA);
  rB += dppf<0x128>(rB);
  { float a, b; plswap16(rA, a, b); rA = a + b; }
  { float a, b; plswap16(rB, a, b); rB = a + b; }
  { float a, b; plswap32(rA, a, b); rA = a + b; }
  { float a, b; plswap32(rB, a, b); rB = a + b; }
}

// all-reduce sum within each 8-lane group
__device__ __forceinline__ float grp8_sum(float x) {
  x += dppf<0xB1>(x);
  x += dppf<0x4E>(x);
  x += swzf<0x101F>(x);
  return x;
}

// complex multiply
__device__ __forceinline__ f2 cmul(f2 a, f2 b) {
  f2 bs = __builtin_shufflevector(b, b, 1, 0);
  f2 t  = (f2){-a.y, a.y} * bs;
  return spl(a.x) * b + t;
}

// ---------------- gates on dual state: s[16], sample = r>>3, wire bits = r&7 ----------------
template<int LB>
__device__ __forceinline__ void ry_local(f2* s, float c, float sv) {
#pragma unroll
  for (int r0 = 0; r0 < 16; ++r0) {
    if ((r0 & 7) & (1 << LB)) continue;
    const int r1 = r0 | (1 << LB);
    f2 a0 = s[r0], a1 = s[r1];
    s[r0] = spl(c) * a0 - spl(sv) * a1;
    s[r1] = spl(sv) * a0 + spl(c) * a1;
  }
}
template<int LB>
__device__ __forceinline__ void rz_local(f2* s, f2 phm, f2 php) {
#pragma unroll
  for (int r = 0; r < 16; ++r) s[r] = cmul(s[r], ((r & 7) & (1 << LB)) ? php : phm);
}
template<int M>
__device__ __forceinline__ void ry_lane(f2* s, float c, float se) {
#pragma unroll
  for (int r = 0; r < 16; ++r) {
    f2 p = bfly2<M>(s[r]);
    s[r] = spl(c) * s[r] + spl(se) * p;
  }
}
template<int CB, int TB>
__device__ __forceinline__ void cnot_ll(f2* s) {
#pragma unroll
  for (int r0 = 0; r0 < 16; ++r0) {
    if (!((r0 & 7) & (1 << CB)) || ((r0 & 7) & (1 << TB))) continue;
    const int r1 = r0 | (1 << TB);
    f2 t = s[r0]; s[r0] = s[r1]; s[r1] = t;
  }
}
template<int CB, int TM>
__device__ __forceinline__ void cnot_lt(f2* s) {
#pragma unroll
  for (int r = 0; r < 16; ++r) {
    if (!((r & 7) & (1 << CB))) continue;
    s[r] = bfly2<TM>(s[r]);
  }
}
__device__ __forceinline__ void cnot_bperm(f2* s, int addrB) {
#pragma unroll
  for (int r = 0; r < 16; ++r) {
    s[r].x = bpermf(addrB, s[r].x);
    s[r].y = bpermf(addrB, s[r].y);
  }
}
// CNOT ctrl=m4 (banks 1,3), tgt=m1: masked quad_perm, others keep old
__device__ __forceinline__ void cnot_m4_t1(f2* s) {
#pragma unroll
  for (int r = 0; r < 16; ++r) {
    s[r].x = dppf_keep<0xB1, 0xF, 0xA>(s[r].x);
    s[r].y = dppf_keep<0xB1, 0xF, 0xA>(s[r].y);
  }
}
// CNOT ctrl=m1, tgt=m2: full quad_perm [0,3,2,1]
__device__ __forceinline__ void cnot_m1_t2(f2* s) {
#pragma unroll
  for (int r = 0; r < 16; ++r) {
    s[r].x = dppf<0x6C>(s[r].x);
    s[r].y = dppf<0x6C>(s[r].y);
  }
}
template<int TB>
__device__ __forceinline__ void cnot_tl(f2* s, bool cc) {
#pragma unroll
  for (int r0 = 0; r0 < 16; ++r0) {
    if ((r0 & 7) & (1 << TB)) continue;
    const int r1 = r0 | (1 << TB);
    f2 n0, n1;
    n0.x = cc ? s[r1].x : s[r0].x;  n0.y = cc ? s[r1].y : s[r0].y;
    n1.x = cc ? s[r0].x : s[r1].x;  n1.y = cc ? s[r0].y : s[r1].y;
    s[r0] = n0; s[r1] = n1;
  }
}

// ---------------- prekernel: layer trig table ----------------
__global__ void qpre_kernel(const float* __restrict__ qw, float* __restrict__ ws) {
  int t = threadIdx.x;
  if (t < 27) {
    float s, c; __sincosf(qw[9 + t] * 0.5f, &s, &c);
    ws[2 * t] = c; ws[2 * t + 1] = s;
  }
}

template<bool PRE>
struct Consts {
  const float* qw; const float* ws;
  __device__ __forceinline__ f2 ltrig(int l, int i) const {
    if constexpr (PRE) {
      return ((const f2*)ws)[(l - 1) * 9 + i];
    } else {
      float s, c; __sincosf(qw[l * 9 + i] * 0.5f, &s, &c);
      return (f2){c, s};
    }
  }
};

// One entangling layer (dual-sample). MODE semantics (all exact):
// 1: ancilla birth scalar; 2: CNOT(7,8) bperm, RY(8) dropped; 3: truncated tail.
template<bool PRE, int MODE>
__device__ __forceinline__ void do_layer(f2* st, int lane, const Consts<PRE>& cst, int l,
                                         int addr56, int addr67, int addr78) {
  f2 t[9];
#pragma unroll
  for (int i = 0; i < 9; ++i) t[i] = cst.ltrig(l, i);

  cnot_ll<0, 1>(st);                                       // CNOT(0,1)
  ry_local<0>(st, t[0].x, t[0].y);
  rz_local<0>(st, (f2){t[0].x, -t[0].y}, (f2){t[0].x, t[0].y});  // Z0 inline
  cnot_ll<1, 2>(st);                                       // CNOT(1,2)
  ry_local<1>(st, t[1].x, t[1].y);                         // Z1 deferred
  cnot_lt<2, 4>(st);                                       // CNOT(2,3)
  ry_local<2>(st, t[2].x, t[2].y);                         // Z2 deferred
  cnot_m4_t1(st);                                          // CNOT(3,4)
  { float se = (lane & 4) ? t[3].y : -t[3].y;
    ry_lane<4>(st, t[3].x, se); }                          // Z3 deferred
  cnot_m1_t2(st);                                          // CNOT(4,5)
  { float se = (lane & 1) ? t[4].y : -t[4].y;
    ry_lane<1>(st, t[4].x, se); }                          // Z4 deferred
  cnot_bperm(st, addr56);                                  // CNOT(5,6)
  { float se = (lane & 2) ? t[5].y : -t[5].y;
    ry_lane<2>(st, t[5].x, se); }                          // Z5 deferred
  cnot_bperm(st, addr67);                                  // CNOT(6,7)
  { float se = (lane & 8) ? t[6].y : -t[6].y;
    ry_lane<8>(st, t[6].x, se); }                          // Z6 deferred
  cnot_tl<0>(st, (lane & 16) != 0);                        // CNOT(7,0)
  { float se = (lane & 16) ? t[7].y : -t[7].y;
    ry_lane<16>(st, t[7].x, se); }                         // Z7 deferred

  if constexpr (MODE == 1) {
    const float wsel = (lane & 32) ? ((lane & 16) ? t[8].x : t[8].y)
                                   : ((lane & 16) ? -t[8].y : t[8].x);
#pragma unroll
    for (int r = 0; r < 16; ++r) st[r] = st[r] * spl(wsel);
  }
  if constexpr (MODE == 2) {
    cnot_bperm(st, addr78);                                // CNOT(7,8)
  }
  if constexpr (MODE != 3) {
    // merged deferred phase (shared across both samples)
    f2 L4[4];
#pragma unroll
    for (int k = 0; k < 4; ++k) {
      f2 p1 = (f2){t[1].x, (k & 1) ? t[1].y : -t[1].y};
      f2 p2 = (f2){t[2].x, (k & 2) ? t[2].y : -t[2].y};
      L4[k] = cmul(p1, p2);
    }
    f2 phW = (f2){t[3].x, (lane & 4)  ? t[3].y : -t[3].y};
    phW = cmul(phW, (f2){t[4].x, (lane & 1)  ? t[4].y : -t[4].y});
    phW = cmul(phW, (f2){t[5].x, (lane & 2)  ? t[5].y : -t[5].y});
    phW = cmul(phW, (f2){t[6].x, (lane & 8)  ? t[6].y : -t[6].y});
    phW = cmul(phW, (f2){t[7].x, (lane & 16) ? t[7].y : -t[7].y});
    f2 pr[4];
#pragma unroll
    for (int k = 0; k < 4; ++k) pr[k] = cmul(L4[k], phW);
#pragma unroll
    for (int r = 0; r < 16; ++r) st[r] = cmul(st[r], pr[((r & 7) >> 1) & 3]);
  }
}

// Wire->lane-bit map (wires 0,1,2 = register bits 0,1,2):
//   wire4->m1, wire5->m2, wire3->m4, wire6->m8, wire7->m16, wire8(anc)->m32
template<bool PRE>
__global__ __launch_bounds__(128, 4) void qlayer_kernel(
    const float* __restrict__ x, const float* __restrict__ tstep,
    const float* __restrict__ w_in, const float* __restrict__ b_in,
    const float* __restrict__ g, const float* __restrict__ be,
    const float* __restrict__ qw, const float* __restrict__ w_out,
    const float* __restrict__ b_out, float* __restrict__ out,
    const float* __restrict__ ws)
{
  __shared__ __align__(16) float s_u[2][2][8][4];  // per-wave, per-sample u table
  __shared__ __align__(16) float s_z[2][2][8];     // per-wave, per-sample z table

  const int tid    = threadIdx.x;
  const int lane   = tid & 63;
  const int wv     = tid >> 6;                  // 0..1 (128-thread block)
  const int smpA   = blockIdx.x * 4 + wv * 2;   // this wave's two samples
  const int smpB   = smpA + 1;
  const int jq     = lane & 7;
  const int dbase  = lane << 3;

  const int addr56 = (lane ^ ((lane & 2) << 2)) << 2;
  const int addr67 = (lane ^ ((lane & 8) << 1)) << 2;
  const int addr78 = (lane ^ ((lane & 16) << 1)) << 2;

  // ---------------- input GEMM (w_in loads shared by both samples) ----------------
  const float4* xrA = (const float4*)(x + (size_t)smpA * ND + dbase);
  const float4* xrB = (const float4*)(x + (size_t)smpB * ND + dbase);
  const float4 xaA = xrA[0], xbA = xrA[1];
  const float4 xaB = xrB[0], xbB = xrB[1];
  const f2 a0 = (f2){xaA.x, xaA.y}, a1 = (f2){xaA.z, xaA.w};
  const f2 a2 = (f2){xbA.x, xbA.y}, a3 = (f2){xbA.z, xbA.w};
  const f2 b0 = (f2){xaB.x, xaB.y}, b1 = (f2){xaB.z, xaB.w};
  const f2 b2 = (f2){xbB.x, xbB.y}, b3 = (f2){xbB.z, xbB.w};

  float hA[8], hB[8];
#pragma unroll
  for (int j = 0; j < 8; ++j) {
    const float4* wj = (const float4*)(w_in + j * ND + dbase);
    float4 wa = wj[0], wb = wj[1];
    f2 w0 = (f2){wa.x, wa.y}, w1 = (f2){wa.z, wa.w};
    f2 w2 = (f2){wb.x, wb.y}, w3 = (f2){wb.z, wb.w};
    f2 accA = a0 * w0 + a1 * w1 + a2 * w2 + a3 * w3;
    f2 accB = b0 * w0 + b1 * w1 + b2 * w2 + b3 * w3;
    hA[j] = accA.x + accA.y;
    hB[j] = accB.x + accB.y;
  }
  float HA, HB;
  fold8_allsum2(hA, hB, lane, HA, HB);

  // ---------------- per-qubit tanh+LN+angle (dual) ----------------
  const float t0  = tstep[0];
  const float bj  = b_in[jq];
  const float gj  = g[jq];
  const float bej = be[jq];
  float tjA, tjB;
  {
    float vA = fminf(15.f, fmaxf(-15.f, HA + bj));
    float vB = fminf(15.f, fmaxf(-15.f, HB + bj));
    float eA = __expf(2.f * vA), eB = __expf(2.f * vB);
    tjA = (eA - 1.f) * __builtin_amdgcn_rcpf(eA + 1.f);
    tjB = (eB - 1.f) * __builtin_amdgcn_rcpf(eB + 1.f);
  }
  const float muA = grp8_sum(tjA) * 0.125f;
  const float muB = grp8_sum(tjB) * 0.125f;
  const float dvA = tjA - muA, dvB = tjB - muB;
  const float varA = grp8_sum(dvA * dvA) * 0.125f;
  const float varB = grp8_sum(dvB * dvB) * 0.125f;
  const float angA = dvA * rsqrtf(varA + 1e-5f) * gj + bej + t0;
  const float angB = dvB * rsqrtf(varB + 1e-5f) * gj + bej + t0;

  // ---------------- u vectors (M shared across samples) ----------------
  {
    float s0, c0, s1, c1;
    __sincosf(qw[jq] * 0.5f, &s0, &c0);
    __sincosf(qw[9 + jq] * 0.5f, &s1, &c1);
    f2 M00 = (f2){ c1 * c0, -s1 * c0};
    f2 M01 = (f2){-s1 * s0, -c1 * s0};
    f2 M10 = (f2){ s1 * s0, -c1 * s0};
    f2 M11 = (f2){ c1 * c0,  s1 * c0};
    float saA, caA; __sincosf(angA * 0.5f, &saA, &caA);
    float saB, caB; __sincosf(angB * 0.5f, &saB, &caB);
    f2 v0A = spl(caA) * (f2){caA, -saA};
    f2 v1A = spl(saA) * (f2){saA, -caA};
    f2 v0B = spl(caB) * (f2){caB, -saB};
    f2 v1B = spl(saB) * (f2){saB, -caB};
    f2 u0A = cmul(M00, v0A) + cmul(M01, v1A);
    f2 u1A = cmul(M10, v0A) + cmul(M11, v1A);
    f2 u0B = cmul(M00, v0B) + cmul(M01, v1B);
    f2 u1B = cmul(M10, v0B) + cmul(M11, v1B);
    if (lane < 16) {
      const int sb = lane >> 3;
      f2 u0 = sb ? u0B : u0A;
      f2 u1 = sb ? u1B : u1A;
      *(float4*)&s_u[wv][sb][jq][0] = (float4){u0.x, u0.y, u1.x, u1.y};
    }
  }
  asm volatile("s_waitcnt lgkmcnt(0)" ::: "memory");
  __builtin_amdgcn_sched_barrier(0);

  // ---------------- build MIRRORED product states ----------------
  f2 st[16];
#pragma unroll
  for (int smp = 0; smp < 2; ++smp) {
    const f2* ub = (const f2*)&s_u[wv][smp][0][0];
    f2 r4 = ub[4 * 2 + ((lane >> 0) & 1)];
    f2 r5 = ub[5 * 2 + ((lane >> 1) & 1)];
    f2 r3 = ub[3 * 2 + ((lane >> 2) & 1)];
    f2 r6 = ub[6 * 2 + ((lane >> 3) & 1)];
    f2 r7 = ub[7 * 2 + ((lane >> 4) & 1)];
    f2 hl = cmul(cmul(cmul(cmul(r4, r5), r3), r6), r7);
    f2 u0q0 = ub[0], u1q0 = ub[1], u0q1 = ub[2], u1q1 = ub[3];
    f2 u0q2 = ub[4], u1q2 = ub[5];
    f2 t01[4];
#pragma unroll
    for (int q = 0; q < 4; ++q)
      t01[q] = cmul((q & 1) ? u1q0 : u0q0, (q & 2) ? u1q1 : u0q1);
#pragma unroll
    for (int r = 0; r < 8; ++r)
      st[smp * 8 + r] = cmul(cmul(t01[r & 3], (r & 4) ? u1q2 : u0q2), hl);
  }

  // ---------------- entangling layers ----------------
  Consts<PRE> cst{qw, ws};
  do_layer<PRE, 1>(st, lane, cst, 1, addr56, addr67, addr78);
  do_layer<PRE, 2>(st, lane, cst, 2, addr56, addr67, addr78);
  do_layer<PRE, 3>(st, lane, cst, 3, addr56, addr67, addr78);

  // ---------------- Z expectations (dual) ----------------
  float pA[8], pB[8];
#pragma unroll
  for (int r = 0; r < 8; ++r) {
    pA[r] = st[r].x * st[r].x + st[r].y * st[r].y;
    pB[r] = st[8 + r].x * st[8 + r].x + st[8 + r].y * st[8 + r].y;
  }
  float totA = 0.f, totB = 0.f;
#pragma unroll
  for (int r = 0; r < 8; ++r) { totA += pA[r]; totB += pB[r]; }

  float yA[8], yB[8];
  yA[0] = (pA[0] - pA[1]) + (pA[2] - pA[3]) + (pA[4] - pA[5]) + (pA[6] - pA[7]);
  yB[0] = (pB[0] - pB[1]) + (pB[2] - pB[3]) + (pB[4] - pB[5]) + (pB[6] - pB[7]);
  yA[1] = (pA[0] + pA[1]) - (pA[2] + pA[3]) + (pA[4] + pA[5]) - (pA[6] + pA[7]);
  yB[1] = (pB[0] + pB[1]) - (pB[2] + pB[3]) + (pB[4] + pB[5]) - (pB[6] + pB[7]);
  yA[2] = (pA[0] + pA[1] + pA[2] + pA[3]) - (pA[4] + pA[5] + pA[6] + pA[7]);
  yB[2] = (pB[0] + pB[1] + pB[2] + pB[3]) - (pB[4] + pB[5] + pB[6] + pB[7]);
  yA[3] = (lane & 4)  ? -totA : totA;  yB[3] = (lane & 4)  ? -totB : totB;
  yA[4] = (lane & 1)  ? -totA : totA;  yB[4] = (lane & 1)  ? -totB : totB;
  yA[5] = (lane & 2)  ? -totA : totA;  yB[5] = (lane & 2)  ? -totB : totB;
  yA[6] = (lane & 8)  ? -totA : totA;  yB[6] = (lane & 8)  ? -totB : totB;
  yA[7] = (lane & 16) ? -totA : totA;  yB[7] = (lane & 16) ? -totB : totB;
  float ZA, ZB;
  fold8_allsum2(yA, yB, lane, ZA, ZB);
  if (lane < 16) {
    const int sb = lane >> 3;
    s_z[wv][sb][jq] = sb ? ZB : ZA;
  }
  asm volatile("s_waitcnt lgkmcnt(0)" ::: "memory");
  __builtin_amdgcn_sched_barrier(0);

  const float4 zaA = *(const float4*)&s_z[wv][0][0];
  const float4 zbA = *(const float4*)&s_z[wv][0][4];
  const float4 zaB = *(const float4*)&s_z[wv][1][0];
  const float4 zbB = *(const float4*)&s_z[wv][1][4];

  // ---------------- epilogue (w_out/b_out loads shared) ----------------
  const f2 zA01 = (f2){zaA.x, zaA.y}, zA23 = (f2){zaA.z, zaA.w};
  const f2 zA45 = (f2){zbA.x, zbA.y}, zA67 = (f2){zbA.z, zbA.w};
  const f2 zB01 = (f2){zaB.x, zaB.y}, zB23 = (f2){zaB.z, zaB.w};
  const f2 zB45 = (f2){zbB.x, zbB.y}, zB67 = (f2){zbB.z, zbB.w};
  const float4* wo = (const float4*)(w_out + (size_t)dbase * 8);
  const float4* bo = (const float4*)(b_out + dbase);
  const float4 bo0 = bo[0], bo1 = bo[1];
  const float xkA[8] = {xaA.x, xaA.y, xaA.z, xaA.w, xbA.x, xbA.y, xbA.z, xbA.w};
  const float xkB[8] = {xaB.x, xaB.y, xaB.z, xaB.w, xbB.x, xbB.y, xbB.z, xbB.w};
  const float bk[8]  = {bo0.x, bo0.y, bo0.z, bo0.w, bo1.x, bo1.y, bo1.z, bo1.w};
  float oA[8], oB[8];
#pragma unroll
  for (int k = 0; k < 8; ++k) {
    float4 wa = wo[2 * k];
    float4 wb = wo[2 * k + 1];
    f2 w01 = (f2){wa.x, wa.y}, w23 = (f2){wa.z, wa.w};
    f2 w45 = (f2){wb.x, wb.y}, w67 = (f2){wb.z, wb.w};
    f2 accA = zA01 * w01 + zA23 * w23 + zA45 * w45 + zA67 * w67;
    f2 accB = zB01 * w01 + zB23 * w23 + zB45 * w45 + zB67 * w67;
    oA[k] = xkA[k] + bk[k] + accA.x + accA.y;
    oB[k] = xkB[k] + bk[k] + accB.x + accB.y;
  }
  float4* outA = (float4*)(out + (size_t)smpA * ND + dbase);
  float4* outB = (float4*)(out + (size_t)smpB * ND + dbase);
  outA[0] = (float4){oA[0], oA[1], oA[2], oA[3]};
  outA[1] = (float4){oA[4], oA[5], oA[6], oA[7]};
  outB[0] = (float4){oB[0], oB[1], oB[2], oB[3]};
  outB[1] = (float4){oB[4], oB[5], oB[6], oB[7]};
}

extern "C" void kernel_launch(void* const* d_in, const int* in_sizes, int n_in,
                              void* d_out, int out_size, void* d_ws, size_t ws_size,
                              hipStream_t stream) {
  const float* x     = (const float*)d_in[0];
  const float* ts    = (const float*)d_in[1];
  const float* w_in  = (const float*)d_in[2];
  const float* b_in  = (const float*)d_in[3];
  const float* g     = (const float*)d_in[4];
  const float* be    = (const float*)d_in[5];
  const float* qw    = (const float*)d_in[6];
  const float* w_out = (const float*)d_in[7];
  const float* b_out = (const float*)d_in[8];
  float* out = (float*)d_out;

  const bool pre = (d_ws != nullptr) && (ws_size >= 256);
  if (pre) {
    qpre_kernel<<<dim3(1), dim3(64), 0, stream>>>(qw, (float*)d_ws);
    qlayer_kernel<true><<<dim3(NSAMP / 4), dim3(128), 0, stream>>>(
        x, ts, w_in, b_in, g, be, qw, w_out, b_out, out, (const float*)d_ws);
  } else {
    qlayer_kernel<false><<<dim3(NSAMP / 4), dim3(128), 0, stream>>>(
        x, ts, w_in, b_in, g, be, qw, w_out, b_out, out, (const float*)d_ws);
  }
}